// Round 1
// baseline (3425.979 us; speedup 1.0000x reference)
//
#include <hip/hip_runtime.h>
#include <math.h>

// TransformerLanguageModel forward on MI355X (gfx950).
// Pipeline per call:
//   1) transpose+convert all weights to bf16 B^T form in d_ws (QKV packed per layer)
//   2) embed + positional encoding -> x (f32 residual stream)
//   3) per layer: LN1 -> QKV gemm -> flash-attn -> Wo gemm (+residual)
//                 LN2 -> FF1 gemm (+ReLU) -> FF2 gemm (+residual)
//   4) LNf -> head gemm -> d_out (f32)
// GEMM: 128x128 tile, BK=64, 4 waves, mfma_f32_16x16x32_bf16, global_load_lds(16B).

using u16 = unsigned short;
using u32 = unsigned int;
typedef __attribute__((ext_vector_type(4))) float  f32x4;
typedef __attribute__((ext_vector_type(8))) short  s16x8;
typedef __attribute__((ext_vector_type(8))) __bf16 bf16x8;

__device__ __forceinline__ u16 f2bf(float f) {
  u32 u = __builtin_bit_cast(u32, f);
  u += 0x7fffu + ((u >> 16) & 1u);   // round-to-nearest-even
  return (u16)(u >> 16);
}

__device__ __forceinline__ f32x4 mfma16(s16x8 a, s16x8 b, f32x4 c) {
  return __builtin_amdgcn_mfma_f32_16x16x32_bf16(
      __builtin_bit_cast(bf16x8, a), __builtin_bit_cast(bf16x8, b), c, 0, 0, 0);
}

#define GLD16(gp, lp) __builtin_amdgcn_global_load_lds(                    \
    (const __attribute__((address_space(1))) void*)(gp),                   \
    (__attribute__((address_space(3))) void*)(lp), 16, 0, 0)

// ---------------- weight transpose + f32->bf16 convert ----------------
// out[c][r] = bf16(in[r][c]); 32x32 tiles; z = layer
__global__ __launch_bounds__(256) void transpose_cvt(
    const float* __restrict__ in, u16* __restrict__ out,
    int C, long long inLS, long long outLS, int outRS)
{
  __shared__ float t[32][33];
  int tr = threadIdx.x >> 5, tc = threadIdx.x & 31;
  const float* ip = in + (size_t)blockIdx.z * inLS +
                    ((size_t)blockIdx.x * 32 + tr) * C + blockIdx.y * 32 + tc;
#pragma unroll
  for (int p = 0; p < 4; ++p) t[p * 8 + tr][tc] = ip[(size_t)p * 8 * C];
  __syncthreads();
  u16* op = out + (size_t)blockIdx.z * outLS +
            ((size_t)blockIdx.y * 32 + tr) * outRS + (size_t)blockIdx.x * 32 + tc;
#pragma unroll
  for (int p = 0; p < 4; ++p) op[(size_t)p * 8 * outRS] = f2bf(t[tc][p * 8 + tr]);
}

__global__ __launch_bounds__(256) void pack_bqkv(
    const float* __restrict__ bq, const float* __restrict__ bk,
    const float* __restrict__ bv, float* __restrict__ outb)
{
  int i = blockIdx.x * 256 + threadIdx.x;  // 8*3072 total
  int ly = i / 3072, j = i % 3072;
  float v = (j < 1024) ? bq[ly * 1024 + j]
          : (j < 2048) ? bk[ly * 1024 + (j - 1024)]
                       : bv[ly * 1024 + (j - 2048)];
  outb[i] = v;
}

// ---------------- embedding + positional encoding ----------------
__global__ __launch_bounds__(256) void embed_kernel(
    const int* __restrict__ tokens, const float* __restrict__ embW,
    float* __restrict__ x)
{
  int row = blockIdx.x;            // b*1024 + s
  int s = row & 1023;
  int tok = tokens[row];
  int d0 = threadIdx.x * 4;
  float4 e = *(const float4*)&embW[(size_t)tok * 1024 + d0];
  const float c = -9.210340371976184f / 1024.0f;  // -ln(10000)/D
  float div0 = expf((float)d0 * c);
  float div1 = expf((float)(d0 + 2) * c);
  float sn0, cs0, sn1, cs1;
  sincosf((float)s * div0, &sn0, &cs0);
  sincosf((float)s * div1, &sn1, &cs1);
  float4 r;
  r.x = e.x + sn0; r.y = e.y + cs0; r.z = e.z + sn1; r.w = e.w + cs1;
  *(float4*)&x[(size_t)row * 1024 + d0] = r;
}

// ---------------- layernorm (f32 in -> bf16 out) ----------------
__global__ __launch_bounds__(256) void ln_kernel(
    const float* __restrict__ x, const float* __restrict__ g,
    const float* __restrict__ b, u16* __restrict__ y)
{
  int row = blockIdx.x, tid = threadIdx.x;
  float4 v = *(const float4*)&x[(size_t)row * 1024 + tid * 4];
  float sum = v.x + v.y + v.z + v.w;
  float sq = v.x * v.x + v.y * v.y + v.z * v.z + v.w * v.w;
#pragma unroll
  for (int o = 32; o > 0; o >>= 1) {
    sum += __shfl_xor(sum, o, 64);
    sq  += __shfl_xor(sq,  o, 64);
  }
  __shared__ float ps[8];
  int w = tid >> 6;
  if ((tid & 63) == 0) { ps[w] = sum; ps[4 + w] = sq; }
  __syncthreads();
  sum = ps[0] + ps[1] + ps[2] + ps[3];
  sq  = ps[4] + ps[5] + ps[6] + ps[7];
  float mu = sum * (1.0f / 1024.0f);
  float var = sq * (1.0f / 1024.0f) - mu * mu;
  float rs = rsqrtf(var + 1e-5f);
  float4 gg = *(const float4*)&g[tid * 4];
  float4 bb = *(const float4*)&b[tid * 4];
  u32 lo = (u32)f2bf((v.x - mu) * rs * gg.x + bb.x) |
           ((u32)f2bf((v.y - mu) * rs * gg.y + bb.y) << 16);
  u32 hi = (u32)f2bf((v.z - mu) * rs * gg.z + bb.z) |
           ((u32)f2bf((v.w - mu) * rs * gg.w + bb.w) << 16);
  uint2 o2; o2.x = lo; o2.y = hi;
  *(uint2*)&y[(size_t)row * 1024 + tid * 4] = o2;
}

// ---------------- GEMM: C[M,N] = A[M,K](bf16) @ B^T[N,K](bf16) + bias ----------------
// OMODE 0: bf16 out; 1: f32 out with f32 residual add; 2: f32 out
template<int OMODE, int RELU>
__global__ __launch_bounds__(256) void gemm_bt(
    const u16* __restrict__ A, const u16* __restrict__ Bt,
    const float* __restrict__ bias, const float* res, void* Cp,
    int M, int N, int K)
{
  __shared__ alignas(16) u16 As[128 * 64];
  __shared__ alignas(16) u16 Bs[128 * 64];
  int tid = threadIdx.x;
  int w = tid >> 6, l = tid & 63;
  int g = l >> 4, lr = l & 15;
  int wm = w >> 1, wn = w & 1;
  int m0 = blockIdx.y * 128, n0 = blockIdx.x * 128;
  f32x4 acc[4][4];
#pragma unroll
  for (int i = 0; i < 4; ++i)
#pragma unroll
    for (int j = 0; j < 4; ++j) acc[i][j] = f32x4{0.f, 0.f, 0.f, 0.f};
  int srow = tid >> 3, scol = (tid & 7) * 8;
  const u16* Ab = A  + (size_t)(m0 + srow) * K + scol;
  const u16* Bb = Bt + (size_t)(n0 + srow) * K + scol;
  int nk = K >> 6;
  for (int kt = 0; kt < nk; ++kt) {
    int k0 = kt << 6;
#pragma unroll
    for (int i = 0; i < 4; ++i) {
      GLD16(Ab + (size_t)(i * 32) * K + k0, As + i * 2048 + w * 512);
      GLD16(Bb + (size_t)(i * 32) * K + k0, Bs + i * 2048 + w * 512);
    }
    __syncthreads();
    s16x8 af[4][2], bf[4][2];
#pragma unroll
    for (int mt = 0; mt < 4; ++mt)
#pragma unroll
      for (int ks = 0; ks < 2; ++ks)
        af[mt][ks] = *(const s16x8*)&As[(wm * 64 + mt * 16 + lr) * 64 + ks * 32 + g * 8];
#pragma unroll
    for (int nt = 0; nt < 4; ++nt)
#pragma unroll
      for (int ks = 0; ks < 2; ++ks)
        bf[nt][ks] = *(const s16x8*)&Bs[(wn * 64 + nt * 16 + lr) * 64 + ks * 32 + g * 8];
#pragma unroll
    for (int ks = 0; ks < 2; ++ks)
#pragma unroll
      for (int mt = 0; mt < 4; ++mt)
#pragma unroll
        for (int nt = 0; nt < 4; ++nt)
          acc[mt][nt] = mfma16(af[mt][ks], bf[nt][ks], acc[mt][nt]);
    __syncthreads();
  }
#pragma unroll
  for (int mt = 0; mt < 4; ++mt) {
    int row = m0 + wm * 64 + mt * 16 + g * 4;
#pragma unroll
    for (int nt = 0; nt < 4; ++nt) {
      int col = n0 + wn * 64 + nt * 16 + lr;
      float bv = bias[col];
#pragma unroll
      for (int r = 0; r < 4; ++r) {
        float v = acc[mt][nt][r] + bv;
        if (RELU) v = fmaxf(v, 0.f);
        size_t idx = (size_t)(row + r) * N + col;
        if (OMODE == 0)      ((u16*)Cp)[idx] = f2bf(v);
        else if (OMODE == 1) ((float*)Cp)[idx] = v + res[idx];
        else                 ((float*)Cp)[idx] = v;
      }
    }
  }
}

// ---------------- flash attention ----------------
// qkv: [4096][3072] bf16 (Q|K|V per 1024 cols, head h at cols h*64..h*64+63)
// grid: (B*H=64, S/64=16); block 256 (4 waves x 16 q-rows)
__global__ __launch_bounds__(256) void attn_kernel(
    const u16* __restrict__ qkv, u16* __restrict__ outp)
{
  int b = blockIdx.x >> 4, h = blockIdx.x & 15;
  int q0 = blockIdx.y << 6;
  int tid = threadIdx.x, w = tid >> 6, l = tid & 63;
  int g = l >> 4, lr = l & 15;
  const int RS = 3072;
  const u16* base = qkv + (size_t)b * 1024 * RS + h * 64;
  const u16* Qb = base;
  const u16* Kb = base + 1024;
  const u16* Vb = base + 2048;
  __shared__ alignas(16) u16 Plds[4][1024];  // per-wave 16x64 P tile (swizzled)
  __shared__ alignas(16) u16 Vt[4096];       // 64(d) x 64(key) V^T tile (swizzled)
  char* Pw = (char*)&Plds[w][0];

  s16x8 qf[2];
#pragma unroll
  for (int ks = 0; ks < 2; ++ks)
    qf[ks] = *(const s16x8*)&Qb[(size_t)(q0 + w * 16 + lr) * RS + ks * 32 + g * 8];

  f32x4 o[4];
#pragma unroll
  for (int n = 0; n < 4; ++n) o[n] = f32x4{0.f, 0.f, 0.f, 0.f};
  float mr[4] = {-INFINITY, -INFINITY, -INFINITY, -INFINITY};
  float ls[4] = {0.f, 0.f, 0.f, 0.f};

  int ntile = (q0 >> 6) + 1;   // causal: only tiles with kv0 <= q0+63
  for (int kt = 0; kt < ntile; ++kt) {
    int kv0 = kt << 6;
    // ---- QK^T: 16x64 scores per wave ----
    f32x4 sc[4];
#pragma unroll
    for (int t = 0; t < 4; ++t) sc[t] = f32x4{0.f, 0.f, 0.f, 0.f};
#pragma unroll
    for (int ks = 0; ks < 2; ++ks)
#pragma unroll
      for (int t = 0; t < 4; ++t) {
        s16x8 kf = *(const s16x8*)&Kb[(size_t)(kv0 + t * 16 + lr) * RS + ks * 32 + g * 8];
        sc[t] = mfma16(qf[ks], kf, sc[t]);
      }
    // ---- stage V^T into LDS (cooperative, swizzled) ----
#pragma unroll
    for (int p = 0; p < 2; ++p) {
      int key = p * 32 + (tid >> 3);
      int d0 = (tid & 7) * 8;
      s16x8 vrow = *(const s16x8*)&Vb[(size_t)(kv0 + key) * RS + d0];
#pragma unroll
      for (int j = 0; j < 8; ++j) {
        int d = d0 + j;
        int byt = (d * 128 + key * 2) ^ ((d & 7) << 4);
        *(u16*)((char*)Vt + byt) = (u16)vrow[j];
      }
    }
    // ---- scale + causal mask + online softmax ----
    float p4[4][4];
    float tmax[4] = {-INFINITY, -INFINITY, -INFINITY, -INFINITY};
    int qr_base = q0 + w * 16 + g * 4;
#pragma unroll
    for (int t = 0; t < 4; ++t) {
      int key = kv0 + t * 16 + lr;
#pragma unroll
      for (int r = 0; r < 4; ++r) {
        float s = sc[t][r] * 0.125f;
        s = (key <= qr_base + r) ? s : -1e30f;
        p4[t][r] = s;
        tmax[r] = fmaxf(tmax[r], s);
      }
    }
#pragma unroll
    for (int off = 1; off < 16; off <<= 1)
#pragma unroll
      for (int r = 0; r < 4; ++r) tmax[r] = fmaxf(tmax[r], __shfl_xor(tmax[r], off, 64));
    float corr[4], rsum[4];
#pragma unroll
    for (int r = 0; r < 4; ++r) {
      float mn = fmaxf(mr[r], tmax[r]);
      corr[r] = __expf(mr[r] - mn);
      mr[r] = mn;
      rsum[r] = 0.f;
    }
#pragma unroll
    for (int t = 0; t < 4; ++t)
#pragma unroll
      for (int r = 0; r < 4; ++r) {
        float e = __expf(p4[t][r] - mr[r]);
        p4[t][r] = e;
        rsum[r] += e;
      }
#pragma unroll
    for (int off = 1; off < 16; off <<= 1)
#pragma unroll
      for (int r = 0; r < 4; ++r) rsum[r] += __shfl_xor(rsum[r], off, 64);
#pragma unroll
    for (int r = 0; r < 4; ++r) ls[r] = ls[r] * corr[r] + rsum[r];
#pragma unroll
    for (int n = 0; n < 4; ++n)
#pragma unroll
      for (int r = 0; r < 4; ++r) o[n][r] *= corr[r];
    // ---- P -> per-wave LDS (bf16, swizzled) ----
#pragma unroll
    for (int t = 0; t < 4; ++t)
#pragma unroll
      for (int r = 0; r < 4; ++r) {
        int prow = g * 4 + r;
        int byt = (prow * 128 + (t * 16 + lr) * 2) ^ ((prow & 7) << 4);
        *(u16*)(Pw + byt) = f2bf(p4[t][r]);
      }
    __syncthreads();
    // ---- PV: o += P @ V ----
#pragma unroll
    for (int ks = 0; ks < 2; ++ks) {
      int ab = (lr * 128 + ks * 64 + g * 16) ^ ((lr & 7) << 4);
      s16x8 pa = *(const s16x8*)(Pw + ab);
#pragma unroll
      for (int n = 0; n < 4; ++n) {
        int vb2 = ((n * 16 + lr) * 128 + ks * 64 + g * 16) ^ ((lr & 7) << 4);
        s16x8 vfr = *(const s16x8*)((const char*)Vt + vb2);
        o[n] = mfma16(pa, vfr, o[n]);
      }
    }
    __syncthreads();
  }
#pragma unroll
  for (int n = 0; n < 4; ++n)
#pragma unroll
    for (int r = 0; r < 4; ++r) {
      float v = o[n][r] / ls[r];
      outp[(size_t)(b * 1024 + q0 + w * 16 + g * 4 + r) * 1024 + h * 64 + n * 16 + lr] = f2bf(v);
    }
}

// ---------------- launch ----------------
extern "C" void kernel_launch(void* const* d_in, const int* in_sizes, int n_in,
                              void* d_out, int out_size, void* d_ws, size_t ws_size,
                              hipStream_t stream)
{
  const int*   tokens = (const int*)  d_in[0];
  const float* embW   = (const float*)d_in[1];
  const float* Wq     = (const float*)d_in[2];
  const float* bq     = (const float*)d_in[3];
  const float* Wk     = (const float*)d_in[4];
  const float* bk     = (const float*)d_in[5];
  const float* Wv     = (const float*)d_in[6];
  const float* bv     = (const float*)d_in[7];
  const float* Wo     = (const float*)d_in[8];
  const float* bo     = (const float*)d_in[9];
  const float* ln1g   = (const float*)d_in[10];
  const float* ln1b   = (const float*)d_in[11];
  const float* ln2g   = (const float*)d_in[12];
  const float* ln2b   = (const float*)d_in[13];
  const float* W1     = (const float*)d_in[14];
  const float* b1     = (const float*)d_in[15];
  const float* W2     = (const float*)d_in[16];
  const float* b2     = (const float*)d_in[17];
  const float* lnfg   = (const float*)d_in[18];
  const float* lnfb   = (const float*)d_in[19];
  const float* headW  = (const float*)d_in[20];
  const float* headb  = (const float*)d_in[21];
  (void)in_sizes; (void)n_in; (void)out_size;

  char* ws = (char*)d_ws;
  u16*   qkvT = (u16*)(ws);               // [8][3072][1024] bf16  (Wq|Wk|Wv transposed)
  u16*   woT  = (u16*)(ws + 50331648);    // [8][1024][1024]
  u16*   w1T  = (u16*)(ws + 67108864);    // [8][4096][1024]
  u16*   w2T  = (u16*)(ws + 134217728);   // [8][1024][4096]
  u16*   headT= (u16*)(ws + 201326592);   // [32000][1024]
  float* bqkv = (float*)(ws + 266862592); // [8][3072]
  float* x    = (float*)(ws + 266960896); // [4096][1024] f32 residual stream
  u16*   y    = (u16*)(ws + 283738112);   // [4096][1024] bf16 LN output
  u16*   qkv  = (u16*)(ws + 292126720);   // [4096][3072] bf16
  u16*   attno= (u16*)(ws + 317292544);   // [4096][1024] bf16
  u16*   h1   = (u16*)(ws + 325681152);   // [4096][4096] bf16
  if (ws_size < 359235584ull) return;     // need ~360 MB scratch

  dim3 blk(256);
  // weight prep
  transpose_cvt<<<dim3(32, 32, 8),  blk, 0, stream>>>(Wq, qkvT,           1024,  1048576LL, 3145728LL, 1024);
  transpose_cvt<<<dim3(32, 32, 8),  blk, 0, stream>>>(Wk, qkvT + 1048576, 1024,  1048576LL, 3145728LL, 1024);
  transpose_cvt<<<dim3(32, 32, 8),  blk, 0, stream>>>(Wv, qkvT + 2097152, 1024,  1048576LL, 3145728LL, 1024);
  transpose_cvt<<<dim3(32, 32, 8),  blk, 0, stream>>>(Wo, woT,            1024,  1048576LL, 1048576LL, 1024);
  transpose_cvt<<<dim3(32, 128, 8), blk, 0, stream>>>(W1, w1T,            4096,  4194304LL, 4194304LL, 1024);
  transpose_cvt<<<dim3(128, 32, 8), blk, 0, stream>>>(W2, w2T,            1024,  4194304LL, 4194304LL, 4096);
  transpose_cvt<<<dim3(32, 1000, 1),blk, 0, stream>>>(headW, headT,       32000, 0LL,       0LL,       1024);
  pack_bqkv<<<96, blk, 0, stream>>>(bq, bk, bv, bqkv);
  // embedding
  embed_kernel<<<4096, blk, 0, stream>>>(tokens, embW, x);
  // layers
  for (int ly = 0; ly < 8; ++ly) {
    ln_kernel<<<4096, blk, 0, stream>>>(x, ln1g + ly * 1024, ln1b + ly * 1024, y);
    gemm_bt<0, 0><<<dim3(24, 32), blk, 0, stream>>>(y, qkvT + (size_t)ly * 3145728,
        bqkv + ly * 3072, nullptr, qkv, 4096, 3072, 1024);
    attn_kernel<<<dim3(64, 16), blk, 0, stream>>>(qkv, attno);
    gemm_bt<1, 0><<<dim3(8, 32), blk, 0, stream>>>(attno, woT + (size_t)ly * 1048576,
        bo + ly * 1024, x, x, 4096, 1024, 1024);
    ln_kernel<<<4096, blk, 0, stream>>>(x, ln2g + ly * 1024, ln2b + ly * 1024, y);
    gemm_bt<0, 1><<<dim3(32, 32), blk, 0, stream>>>(y, w1T + (size_t)ly * 4194304,
        b1 + ly * 4096, nullptr, h1, 4096, 4096, 1024);
    gemm_bt<1, 0><<<dim3(8, 32), blk, 0, stream>>>(h1, w2T + (size_t)ly * 4194304,
        b2 + ly * 1024, x, x, 4096, 1024, 4096);
  }
  // final LN + head
  ln_kernel<<<4096, blk, 0, stream>>>(x, lnfg, lnfb, y);
  gemm_bt<2, 0><<<dim3(250, 32), blk, 0, stream>>>(y, headT, headb, nullptr,
      (float*)d_out, 4096, 32000, 1024);
}

// Round 2
// 3065.547 us; speedup vs baseline: 1.1176x; 1.1176x over previous
//
#include <hip/hip_runtime.h>
#include <math.h>

// TransformerLanguageModel forward on MI355X (gfx950).
//   1) transpose+convert all weights to bf16 B^T form in d_ws (QKV packed per layer)
//   2) embed + positional encoding -> x (f32 residual stream)
//   3) per layer: LN1 -> QKV gemm256 -> flash-attn -> Wo gemm (+residual)
//                 LN2 -> FF1 gemm256 (+ReLU) -> FF2 gemm (+residual)
//   4) LNf -> head gemm256 -> d_out (f32)
// gemm256: 256x256 tile, BK=32, 8 waves, ring-3 LDS pipeline, counted vmcnt,
//          LDS XOR swizzle (T2), setprio (T5), XCD swizzle (T1).

using u16 = unsigned short;
using u32 = unsigned int;
typedef __attribute__((ext_vector_type(4))) float  f32x4;
typedef __attribute__((ext_vector_type(8))) short  s16x8;
typedef __attribute__((ext_vector_type(8))) __bf16 bf16x8;

__device__ __forceinline__ u16 f2bf(float f) {
  u32 u = __builtin_bit_cast(u32, f);
  u += 0x7fffu + ((u >> 16) & 1u);   // round-to-nearest-even
  return (u16)(u >> 16);
}

__device__ __forceinline__ f32x4 mfma16(s16x8 a, s16x8 b, f32x4 c) {
  return __builtin_amdgcn_mfma_f32_16x16x32_bf16(
      __builtin_bit_cast(bf16x8, a), __builtin_bit_cast(bf16x8, b), c, 0, 0, 0);
}

#define GLD16(gp, lp) __builtin_amdgcn_global_load_lds(                    \
    (const __attribute__((address_space(1))) void*)(gp),                   \
    (__attribute__((address_space(3))) void*)(lp), 16, 0, 0)

// ---------------- weight transpose + f32->bf16 convert ----------------
__global__ __launch_bounds__(256) void transpose_cvt(
    const float* __restrict__ in, u16* __restrict__ out,
    int C, long long inLS, long long outLS, int outRS)
{
  __shared__ float t[32][33];
  int tr = threadIdx.x >> 5, tc = threadIdx.x & 31;
  const float* ip = in + (size_t)blockIdx.z * inLS +
                    ((size_t)blockIdx.x * 32 + tr) * C + blockIdx.y * 32 + tc;
#pragma unroll
  for (int p = 0; p < 4; ++p) t[p * 8 + tr][tc] = ip[(size_t)p * 8 * C];
  __syncthreads();
  u16* op = out + (size_t)blockIdx.z * outLS +
            ((size_t)blockIdx.y * 32 + tr) * outRS + (size_t)blockIdx.x * 32 + tc;
#pragma unroll
  for (int p = 0; p < 4; ++p) op[(size_t)p * 8 * outRS] = f2bf(t[tc][p * 8 + tr]);
}

__global__ __launch_bounds__(256) void pack_bqkv(
    const float* __restrict__ bq, const float* __restrict__ bk,
    const float* __restrict__ bv, float* __restrict__ outb)
{
  int i = blockIdx.x * 256 + threadIdx.x;  // 8*3072 total
  int ly = i / 3072, j = i % 3072;
  float v = (j < 1024) ? bq[ly * 1024 + j]
          : (j < 2048) ? bk[ly * 1024 + (j - 1024)]
                       : bv[ly * 1024 + (j - 2048)];
  outb[i] = v;
}

// ---------------- embedding + positional encoding ----------------
__global__ __launch_bounds__(256) void embed_kernel(
    const int* __restrict__ tokens, const float* __restrict__ embW,
    float* __restrict__ x)
{
  int row = blockIdx.x;            // b*1024 + s
  int s = row & 1023;
  int tok = tokens[row];
  int d0 = threadIdx.x * 4;
  float4 e = *(const float4*)&embW[(size_t)tok * 1024 + d0];
  const float c = -9.210340371976184f / 1024.0f;  // -ln(10000)/D
  float div0 = expf((float)d0 * c);
  float div1 = expf((float)(d0 + 2) * c);
  float sn0, cs0, sn1, cs1;
  sincosf((float)s * div0, &sn0, &cs0);
  sincosf((float)s * div1, &sn1, &cs1);
  float4 r;
  r.x = e.x + sn0; r.y = e.y + cs0; r.z = e.z + sn1; r.w = e.w + cs1;
  *(float4*)&x[(size_t)row * 1024 + d0] = r;
}

// ---------------- layernorm (f32 in -> bf16 out) ----------------
__global__ __launch_bounds__(256) void ln_kernel(
    const float* __restrict__ x, const float* __restrict__ g,
    const float* __restrict__ b, u16* __restrict__ y)
{
  int row = blockIdx.x, tid = threadIdx.x;
  float4 v = *(const float4*)&x[(size_t)row * 1024 + tid * 4];
  float sum = v.x + v.y + v.z + v.w;
  float sq = v.x * v.x + v.y * v.y + v.z * v.z + v.w * v.w;
#pragma unroll
  for (int o = 32; o > 0; o >>= 1) {
    sum += __shfl_xor(sum, o, 64);
    sq  += __shfl_xor(sq,  o, 64);
  }
  __shared__ float ps[8];
  int w = tid >> 6;
  if ((tid & 63) == 0) { ps[w] = sum; ps[4 + w] = sq; }
  __syncthreads();
  sum = ps[0] + ps[1] + ps[2] + ps[3];
  sq  = ps[4] + ps[5] + ps[6] + ps[7];
  float mu = sum * (1.0f / 1024.0f);
  float var = sq * (1.0f / 1024.0f) - mu * mu;
  float rs = rsqrtf(var + 1e-5f);
  float4 gg = *(const float4*)&g[tid * 4];
  float4 bb = *(const float4*)&b[tid * 4];
  u32 lo = (u32)f2bf((v.x - mu) * rs * gg.x + bb.x) |
           ((u32)f2bf((v.y - mu) * rs * gg.y + bb.y) << 16);
  u32 hi = (u32)f2bf((v.z - mu) * rs * gg.z + bb.z) |
           ((u32)f2bf((v.w - mu) * rs * gg.w + bb.w) << 16);
  uint2 o2; o2.x = lo; o2.y = hi;
  *(uint2*)&y[(size_t)row * 1024 + tid * 4] = o2;
}

// ---------------- GEMM 128x128 (2-barrier structure) for N=1024 shapes ----
// OMODE 0: bf16 out; 1: f32 out with f32 residual add; 2: f32 out
template<int OMODE, int RELU>
__global__ __launch_bounds__(256) void gemm_bt(
    const u16* __restrict__ A, const u16* __restrict__ Bt,
    const float* __restrict__ bias, const float* res, void* Cp,
    int M, int N, int K)
{
  __shared__ alignas(16) u16 As[128 * 64];
  __shared__ alignas(16) u16 Bs[128 * 64];
  int tid = threadIdx.x;
  int w = tid >> 6, l = tid & 63;
  int g = l >> 4, lr = l & 15;
  int wm = w >> 1, wn = w & 1;
  int m0 = blockIdx.y * 128, n0 = blockIdx.x * 128;
  f32x4 acc[4][4];
#pragma unroll
  for (int i = 0; i < 4; ++i)
#pragma unroll
    for (int j = 0; j < 4; ++j) acc[i][j] = f32x4{0.f, 0.f, 0.f, 0.f};
  int srow = tid >> 3, scol = (tid & 7) * 8;
  const u16* Ab = A  + (size_t)(m0 + srow) * K + scol;
  const u16* Bb = Bt + (size_t)(n0 + srow) * K + scol;
  int nk = K >> 6;
  for (int kt = 0; kt < nk; ++kt) {
    int k0 = kt << 6;
#pragma unroll
    for (int i = 0; i < 4; ++i) {
      GLD16(Ab + (size_t)(i * 32) * K + k0, As + i * 2048 + w * 512);
      GLD16(Bb + (size_t)(i * 32) * K + k0, Bs + i * 2048 + w * 512);
    }
    __syncthreads();
    s16x8 af[4][2], bf[4][2];
#pragma unroll
    for (int mt = 0; mt < 4; ++mt)
#pragma unroll
      for (int ks = 0; ks < 2; ++ks)
        af[mt][ks] = *(const s16x8*)&As[(wm * 64 + mt * 16 + lr) * 64 + ks * 32 + g * 8];
#pragma unroll
    for (int nt = 0; nt < 4; ++nt)
#pragma unroll
      for (int ks = 0; ks < 2; ++ks)
        bf[nt][ks] = *(const s16x8*)&Bs[(wn * 64 + nt * 16 + lr) * 64 + ks * 32 + g * 8];
#pragma unroll
    for (int ks = 0; ks < 2; ++ks)
#pragma unroll
      for (int mt = 0; mt < 4; ++mt)
#pragma unroll
        for (int nt = 0; nt < 4; ++nt)
          acc[mt][nt] = mfma16(af[mt][ks], bf[nt][ks], acc[mt][nt]);
    __syncthreads();
  }
#pragma unroll
  for (int mt = 0; mt < 4; ++mt) {
    int row = m0 + wm * 64 + mt * 16 + g * 4;
#pragma unroll
    for (int nt = 0; nt < 4; ++nt) {
      int col = n0 + wn * 64 + nt * 16 + lr;
      float bv = bias[col];
#pragma unroll
      for (int r = 0; r < 4; ++r) {
        float v = acc[mt][nt][r] + bv;
        if (RELU) v = fmaxf(v, 0.f);
        size_t idx = (size_t)(row + r) * N + col;
        if (OMODE == 0)      ((u16*)Cp)[idx] = f2bf(v);
        else if (OMODE == 1) ((float*)Cp)[idx] = v + res[idx];
        else                 ((float*)Cp)[idx] = v;
      }
    }
  }
}

// ---------------- GEMM 256x256, BK=32, 8 waves, ring-3 pipelined ----------
// C[M,N] = A[M,K] @ Bt[N,K] + bias.  OMODE 0: bf16 out; 2: f32 out.
// grid: 1D, nwg = (N/256)*(M/256), nwg % 8 == 0 required.  gy = M/256.
template<int OMODE, int RELU>
__global__ __launch_bounds__(512, 2) void gemm256(
    const u16* __restrict__ A, const u16* __restrict__ Bt,
    const float* __restrict__ bias, void* Cp, int M, int N, int K, int gy)
{
  // ring-3 buffers: each 32 KB = A[256][32] bf16 (8192) | B[256][32] (8192)
  __shared__ alignas(16) u16 lds[3][16384];
  const int tid = threadIdx.x;
  const int w = tid >> 6, l = tid & 63;
  const int g = l >> 4, lr = l & 15;
  const int wm = w >> 2, wn = w & 3;            // 2 x 4 waves, wave tile 128x64
  // XCD-aware swizzle (nwg % 8 == 0 for all our shapes)
  int nwg = gridDim.x;
  int bid = blockIdx.x;
  int swz = (bid & 7) * (nwg >> 3) + (bid >> 3);
  int by = swz % gy, bx = swz / gy;             // by-major: consecutive share B panel
  int m0 = by << 8, n0 = bx << 8;

  // staging geometry: thread stages 2x16B for A and 2x16B for B per K-tile.
  // LDS dest is linear (idx*16 bytes); global src is inverse-swizzled.
  const u16* Ag[2]; const u16* Bg[2]; int dstE[2];
#pragma unroll
  for (int s2 = 0; s2 < 2; ++s2) {
    int idx = s2 * 512 + tid;
    int row = idx >> 2;
    int ch = (idx & 3) ^ (row & 3);             // involutive chunk swizzle
    Ag[s2] = A  + (size_t)(m0 + row) * K + ch * 8;
    Bg[s2] = Bt + (size_t)(n0 + row) * K + ch * 8;
    dstE[s2] = idx * 8;                         // element offset in region
  }
  // fragment read offsets (elements), swizzled: col ^= ((row&3)<<3)
  const int colx = (g * 8) ^ ((lr & 3) << 3);
  const int aoff = (wm * 128 + lr) * 32 + colx;  // + mf*512
  const int boff = 8192 + (wn * 64 + lr) * 32 + colx;  // + nf*512

  f32x4 acc[8][4];
#pragma unroll
  for (int i = 0; i < 8; ++i)
#pragma unroll
    for (int j = 0; j < 4; ++j) acc[i][j] = f32x4{0.f, 0.f, 0.f, 0.f};

  const int nk = K >> 5;
  // prologue: stage tiles 0 and 1
#pragma unroll
  for (int pt = 0; pt < 2; ++pt) {
    u16* buf = &lds[pt][0];
#pragma unroll
    for (int s2 = 0; s2 < 2; ++s2) GLD16(Ag[s2] + pt * 32, buf + dstE[s2]);
#pragma unroll
    for (int s2 = 0; s2 < 2; ++s2) GLD16(Bg[s2] + pt * 32, buf + 8192 + dstE[s2]);
  }
  asm volatile("s_waitcnt vmcnt(4)" ::: "memory");
  __builtin_amdgcn_s_barrier();

  u16* p0 = &lds[0][0];  // current
  u16* p1 = &lds[1][0];  // next (staged / landing)
  u16* p2 = &lds[2][0];  // staging target (t+2)
  for (int t = 0; t < nk; ++t) {
    const int k2 = t * 32 + 64;
    const bool st = (t + 2 < nk);
    s16x8 af[4], bf4[4];
    // ---- phase 0: A-frags mf 0..3 + all B-frags; stage A(t+2) ----
#pragma unroll
    for (int i = 0; i < 4; ++i) af[i] = *(const s16x8*)&p0[aoff + i * 512];
#pragma unroll
    for (int j = 0; j < 4; ++j) bf4[j] = *(const s16x8*)&p0[boff + j * 512];
    if (st) {
#pragma unroll
      for (int s2 = 0; s2 < 2; ++s2) GLD16(Ag[s2] + k2, p2 + dstE[s2]);
    }
    __builtin_amdgcn_s_barrier();
    asm volatile("s_waitcnt lgkmcnt(0)" ::: "memory");
    __builtin_amdgcn_sched_barrier(0);
    __builtin_amdgcn_s_setprio(1);
#pragma unroll
    for (int i = 0; i < 4; ++i)
#pragma unroll
      for (int j = 0; j < 4; ++j) acc[i][j] = mfma16(af[i], bf4[j], acc[i][j]);
    __builtin_amdgcn_s_setprio(0);
    __builtin_amdgcn_s_barrier();
    // ---- phase 1: A-frags mf 4..7 (B reused); stage B(t+2) ----
#pragma unroll
    for (int i = 0; i < 4; ++i) af[i] = *(const s16x8*)&p0[aoff + (4 + i) * 512];
    if (st) {
#pragma unroll
      for (int s2 = 0; s2 < 2; ++s2) GLD16(Bg[s2] + k2, p2 + 8192 + dstE[s2]);
    }
    __builtin_amdgcn_s_barrier();
    asm volatile("s_waitcnt lgkmcnt(0)" ::: "memory");
    __builtin_amdgcn_sched_barrier(0);
    __builtin_amdgcn_s_setprio(1);
#pragma unroll
    for (int i = 0; i < 4; ++i)
#pragma unroll
      for (int j = 0; j < 4; ++j) acc[4 + i][j] = mfma16(af[i], bf4[j], acc[4 + i][j]);
    __builtin_amdgcn_s_setprio(0);
    // counted drain: next tile (t+1) fully landed; t+2 (4 loads) stays in flight
    if (st)                asm volatile("s_waitcnt vmcnt(4)" ::: "memory");
    else if (t + 1 < nk)   asm volatile("s_waitcnt vmcnt(0)" ::: "memory");
    __builtin_amdgcn_s_barrier();
    u16* tmp = p0; p0 = p1; p1 = p2; p2 = tmp;  // rotate ring
  }
  // ---- epilogue ----
#pragma unroll
  for (int mf = 0; mf < 8; ++mf) {
    int row = m0 + wm * 128 + mf * 16 + g * 4;
#pragma unroll
    for (int nf = 0; nf < 4; ++nf) {
      int col = n0 + wn * 64 + nf * 16 + lr;
      float bv = bias[col];
#pragma unroll
      for (int r = 0; r < 4; ++r) {
        float v = acc[mf][nf][r] + bv;
        if (RELU) v = fmaxf(v, 0.f);
        size_t idx = (size_t)(row + r) * N + col;
        if (OMODE == 0) ((u16*)Cp)[idx] = f2bf(v);
        else            ((float*)Cp)[idx] = v;
      }
    }
  }
}

// ---------------- flash attention ----------------
__global__ __launch_bounds__(256) void attn_kernel(
    const u16* __restrict__ qkv, u16* __restrict__ outp)
{
  int b = blockIdx.x >> 4, h = blockIdx.x & 15;
  int q0 = blockIdx.y << 6;
  int tid = threadIdx.x, w = tid >> 6, l = tid & 63;
  int g = l >> 4, lr = l & 15;
  const int RS = 3072;
  const u16* base = qkv + (size_t)b * 1024 * RS + h * 64;
  const u16* Qb = base;
  const u16* Kb = base + 1024;
  const u16* Vb = base + 2048;
  __shared__ alignas(16) u16 Plds[4][1024];
  __shared__ alignas(16) u16 Vt[4096];
  char* Pw = (char*)&Plds[w][0];

  s16x8 qf[2];
#pragma unroll
  for (int ks = 0; ks < 2; ++ks)
    qf[ks] = *(const s16x8*)&Qb[(size_t)(q0 + w * 16 + lr) * RS + ks * 32 + g * 8];

  f32x4 o[4];
#pragma unroll
  for (int n = 0; n < 4; ++n) o[n] = f32x4{0.f, 0.f, 0.f, 0.f};
  float mr[4] = {-INFINITY, -INFINITY, -INFINITY, -INFINITY};
  float ls[4] = {0.f, 0.f, 0.f, 0.f};

  int ntile = (q0 >> 6) + 1;
  for (int kt = 0; kt < ntile; ++kt) {
    int kv0 = kt << 6;
    f32x4 sc[4];
#pragma unroll
    for (int t = 0; t < 4; ++t) sc[t] = f32x4{0.f, 0.f, 0.f, 0.f};
#pragma unroll
    for (int ks = 0; ks < 2; ++ks)
#pragma unroll
      for (int t = 0; t < 4; ++t) {
        s16x8 kf = *(const s16x8*)&Kb[(size_t)(kv0 + t * 16 + lr) * RS + ks * 32 + g * 8];
        sc[t] = mfma16(qf[ks], kf, sc[t]);
      }
#pragma unroll
    for (int p = 0; p < 2; ++p) {
      int key = p * 32 + (tid >> 3);
      int d0 = (tid & 7) * 8;
      s16x8 vrow = *(const s16x8*)&Vb[(size_t)(kv0 + key) * RS + d0];
#pragma unroll
      for (int j = 0; j < 8; ++j) {
        int d = d0 + j;
        int byt = (d * 128 + key * 2) ^ ((d & 7) << 4);
        *(u16*)((char*)Vt + byt) = (u16)vrow[j];
      }
    }
    float p4[4][4];
    float tmax[4] = {-INFINITY, -INFINITY, -INFINITY, -INFINITY};
    int qr_base = q0 + w * 16 + g * 4;
#pragma unroll
    for (int t = 0; t < 4; ++t) {
      int key = kv0 + t * 16 + lr;
#pragma unroll
      for (int r = 0; r < 4; ++r) {
        float s = sc[t][r] * 0.125f;
        s = (key <= qr_base + r) ? s : -1e30f;
        p4[t][r] = s;
        tmax[r] = fmaxf(tmax[r], s);
      }
    }
#pragma unroll
    for (int off = 1; off < 16; off <<= 1)
#pragma unroll
      for (int r = 0; r < 4; ++r) tmax[r] = fmaxf(tmax[r], __shfl_xor(tmax[r], off, 64));
    float corr[4], rsum[4];
#pragma unroll
    for (int r = 0; r < 4; ++r) {
      float mn = fmaxf(mr[r], tmax[r]);
      corr[r] = __expf(mr[r] - mn);
      mr[r] = mn;
      rsum[r] = 0.f;
    }
#pragma unroll
    for (int t = 0; t < 4; ++t)
#pragma unroll
      for (int r = 0; r < 4; ++r) {
        float e = __expf(p4[t][r] - mr[r]);
        p4[t][r] = e;
        rsum[r] += e;
      }
#pragma unroll
    for (int off = 1; off < 16; off <<= 1)
#pragma unroll
      for (int r = 0; r < 4; ++r) rsum[r] += __shfl_xor(rsum[r], off, 64);
#pragma unroll
    for (int r = 0; r < 4; ++r) ls[r] = ls[r] * corr[r] + rsum[r];
#pragma unroll
    for (int n = 0; n < 4; ++n)
#pragma unroll
      for (int r = 0; r < 4; ++r) o[n][r] *= corr[r];
#pragma unroll
    for (int t = 0; t < 4; ++t)
#pragma unroll
      for (int r = 0; r < 4; ++r) {
        int prow = g * 4 + r;
        int byt = (prow * 128 + (t * 16 + lr) * 2) ^ ((prow & 7) << 4);
        *(u16*)(Pw + byt) = f2bf(p4[t][r]);
      }
    __syncthreads();
#pragma unroll
    for (int ks = 0; ks < 2; ++ks) {
      int ab = (lr * 128 + ks * 64 + g * 16) ^ ((lr & 7) << 4);
      s16x8 pa = *(const s16x8*)(Pw + ab);
#pragma unroll
      for (int n = 0; n < 4; ++n) {
        int vb2 = ((n * 16 + lr) * 128 + ks * 64 + g * 16) ^ ((lr & 7) << 4);
        s16x8 vfr = *(const s16x8*)((const char*)Vt + vb2);
        o[n] = mfma16(pa, vfr, o[n]);
      }
    }
    __syncthreads();
  }
#pragma unroll
  for (int n = 0; n < 4; ++n)
#pragma unroll
    for (int r = 0; r < 4; ++r) {
      float v = o[n][r] / ls[r];
      outp[(size_t)(b * 1024 + q0 + w * 16 + g * 4 + r) * 1024 + h * 64 + n * 16 + lr] = f2bf(v);
    }
}

// ---------------- launch ----------------
extern "C" void kernel_launch(void* const* d_in, const int* in_sizes, int n_in,
                              void* d_out, int out_size, void* d_ws, size_t ws_size,
                              hipStream_t stream)
{
  const int*   tokens = (const int*)  d_in[0];
  const float* embW   = (const float*)d_in[1];
  const float* Wq     = (const float*)d_in[2];
  const float* bq     = (const float*)d_in[3];
  const float* Wk     = (const float*)d_in[4];
  const float* bk     = (const float*)d_in[5];
  const float* Wv     = (const float*)d_in[6];
  const float* bv     = (const float*)d_in[7];
  const float* Wo     = (const float*)d_in[8];
  const float* bo     = (const float*)d_in[9];
  const float* ln1g   = (const float*)d_in[10];
  const float* ln1b   = (const float*)d_in[11];
  const float* ln2g   = (const float*)d_in[12];
  const float* ln2b   = (const float*)d_in[13];
  const float* W1     = (const float*)d_in[14];
  const float* b1     = (const float*)d_in[15];
  const float* W2     = (const float*)d_in[16];
  const float* b2     = (const float*)d_in[17];
  const float* lnfg   = (const float*)d_in[18];
  const float* lnfb   = (const float*)d_in[19];
  const float* headW  = (const float*)d_in[20];
  const float* headb  = (const float*)d_in[21];
  (void)in_sizes; (void)n_in; (void)out_size;

  char* ws = (char*)d_ws;
  u16*   qkvT = (u16*)(ws);               // [8][3072][1024] bf16
  u16*   woT  = (u16*)(ws + 50331648);    // [8][1024][1024]
  u16*   w1T  = (u16*)(ws + 67108864);    // [8][4096][1024]
  u16*   w2T  = (u16*)(ws + 134217728);   // [8][1024][4096]
  u16*   headT= (u16*)(ws + 201326592);   // [32000][1024]
  float* bqkv = (float*)(ws + 266862592); // [8][3072]
  float* x    = (float*)(ws + 266960896); // [4096][1024] f32 residual stream
  u16*   y    = (u16*)(ws + 283738112);   // [4096][1024] bf16 LN output
  u16*   qkv  = (u16*)(ws + 292126720);   // [4096][3072] bf16
  u16*   attno= (u16*)(ws + 317292544);   // [4096][1024] bf16
  u16*   h1   = (u16*)(ws + 325681152);   // [4096][4096] bf16
  if (ws_size < 359235584ull) return;     // need ~360 MB scratch

  dim3 blk(256);
  dim3 blk5(512);
  // weight prep
  transpose_cvt<<<dim3(32, 32, 8),  blk, 0, stream>>>(Wq, qkvT,           1024,  1048576LL, 3145728LL, 1024);
  transpose_cvt<<<dim3(32, 32, 8),  blk, 0, stream>>>(Wk, qkvT + 1048576, 1024,  1048576LL, 3145728LL, 1024);
  transpose_cvt<<<dim3(32, 32, 8),  blk, 0, stream>>>(Wv, qkvT + 2097152, 1024,  1048576LL, 3145728LL, 1024);
  transpose_cvt<<<dim3(32, 32, 8),  blk, 0, stream>>>(Wo, woT,            1024,  1048576LL, 1048576LL, 1024);
  transpose_cvt<<<dim3(32, 128, 8), blk, 0, stream>>>(W1, w1T,            4096,  4194304LL, 4194304LL, 1024);
  transpose_cvt<<<dim3(128, 32, 8), blk, 0, stream>>>(W2, w2T,            1024,  4194304LL, 4194304LL, 4096);
  transpose_cvt<<<dim3(32, 1000, 1),blk, 0, stream>>>(headW, headT,       32000, 0LL,       0LL,       1024);
  pack_bqkv<<<96, blk, 0, stream>>>(bq, bk, bv, bqkv);
  // embedding
  embed_kernel<<<4096, blk, 0, stream>>>(tokens, embW, x);
  // layers
  for (int ly = 0; ly < 8; ++ly) {
    ln_kernel<<<4096, blk, 0, stream>>>(x, ln1g + ly * 1024, ln1b + ly * 1024, y);
    gemm256<0, 0><<<192, blk5, 0, stream>>>(y, qkvT + (size_t)ly * 3145728,
        bqkv + ly * 3072, qkv, 4096, 3072, 1024, 16);
    attn_kernel<<<dim3(64, 16), blk, 0, stream>>>(qkv, attno);
    gemm_bt<1, 0><<<dim3(8, 32), blk, 0, stream>>>(attno, woT + (size_t)ly * 1048576,
        bo + ly * 1024, x, x, 4096, 1024, 1024);
    ln_kernel<<<4096, blk, 0, stream>>>(x, ln2g + ly * 1024, ln2b + ly * 1024, y);
    gemm256<0, 1><<<256, blk5, 0, stream>>>(y, w1T + (size_t)ly * 4194304,
        b1 + ly * 4096, h1, 4096, 4096, 1024, 16);
    gemm_bt<1, 0><<<dim3(8, 32), blk, 0, stream>>>(h1, w2T + (size_t)ly * 4194304,
        b2 + ly * 1024, x, x, 4096, 1024, 4096);
  }
  // final LN + head
  ln_kernel<<<4096, blk, 0, stream>>>(x, lnfg, lnfb, y);
  gemm256<2, 0><<<2000, blk5, 0, stream>>>(y, headT, headb,
      (float*)d_out, 4096, 32000, 1024, 16);
}

// Round 3
// 2957.703 us; speedup vs baseline: 1.1583x; 1.0365x over previous
//
#include <hip/hip_runtime.h>
#include <math.h>

// TransformerLanguageModel forward on MI355X (gfx950).
//   1) transpose+convert all weights to bf16 B^T form in d_ws (QKV packed per layer)
//   2) embed + positional encoding -> x (f32 residual stream)
//   3) per layer: LN1 -> QKV gemm256 -> flash-attn -> Wo gemm (+residual)
//                 LN2 -> FF1 gemm256 (+ReLU) -> FF2 gemm (+residual)
//   4) LNf -> head gemm256 -> d_out (f32)
// gemm256: 256x256 tile, BK=32, 8 waves, ring-4 LDS pipeline (depth 3),
//          counted vmcnt(8), LDS XOR swizzle chunk^=(row>>1)&3 (2-way, free),
//          setprio around MFMA, XCD-bijective block swizzle.

using u16 = unsigned short;
using u32 = unsigned int;
typedef __attribute__((ext_vector_type(4))) float  f32x4;
typedef __attribute__((ext_vector_type(8))) short  s16x8;
typedef __attribute__((ext_vector_type(8))) __bf16 bf16x8;

__device__ __forceinline__ u16 f2bf(float f) {
  u32 u = __builtin_bit_cast(u32, f);
  u += 0x7fffu + ((u >> 16) & 1u);   // round-to-nearest-even
  return (u16)(u >> 16);
}

__device__ __forceinline__ f32x4 mfma16(s16x8 a, s16x8 b, f32x4 c) {
  return __builtin_amdgcn_mfma_f32_16x16x32_bf16(
      __builtin_bit_cast(bf16x8, a), __builtin_bit_cast(bf16x8, b), c, 0, 0, 0);
}

#define GLD16(gp, lp) __builtin_amdgcn_global_load_lds(                    \
    (const __attribute__((address_space(1))) void*)(gp),                   \
    (__attribute__((address_space(3))) void*)(lp), 16, 0, 0)

// ---------------- weight transpose + f32->bf16 convert ----------------
__global__ __launch_bounds__(256) void transpose_cvt(
    const float* __restrict__ in, u16* __restrict__ out,
    int C, long long inLS, long long outLS, int outRS)
{
  __shared__ float t[32][33];
  int tr = threadIdx.x >> 5, tc = threadIdx.x & 31;
  const float* ip = in + (size_t)blockIdx.z * inLS +
                    ((size_t)blockIdx.x * 32 + tr) * C + blockIdx.y * 32 + tc;
#pragma unroll
  for (int p = 0; p < 4; ++p) t[p * 8 + tr][tc] = ip[(size_t)p * 8 * C];
  __syncthreads();
  u16* op = out + (size_t)blockIdx.z * outLS +
            ((size_t)blockIdx.y * 32 + tr) * outRS + (size_t)blockIdx.x * 32 + tc;
#pragma unroll
  for (int p = 0; p < 4; ++p) op[(size_t)p * 8 * outRS] = f2bf(t[tc][p * 8 + tr]);
}

__global__ __launch_bounds__(256) void pack_bqkv(
    const float* __restrict__ bq, const float* __restrict__ bk,
    const float* __restrict__ bv, float* __restrict__ outb)
{
  int i = blockIdx.x * 256 + threadIdx.x;  // 8*3072 total
  int ly = i / 3072, j = i % 3072;
  float v = (j < 1024) ? bq[ly * 1024 + j]
          : (j < 2048) ? bk[ly * 1024 + (j - 1024)]
                       : bv[ly * 1024 + (j - 2048)];
  outb[i] = v;
}

// ---------------- embedding + positional encoding ----------------
__global__ __launch_bounds__(256) void embed_kernel(
    const int* __restrict__ tokens, const float* __restrict__ embW,
    float* __restrict__ x)
{
  int row = blockIdx.x;            // b*1024 + s
  int s = row & 1023;
  int tok = tokens[row];
  int d0 = threadIdx.x * 4;
  float4 e = *(const float4*)&embW[(size_t)tok * 1024 + d0];
  const float c = -9.210340371976184f / 1024.0f;  // -ln(10000)/D
  float div0 = expf((float)d0 * c);
  float div1 = expf((float)(d0 + 2) * c);
  float sn0, cs0, sn1, cs1;
  sincosf((float)s * div0, &sn0, &cs0);
  sincosf((float)s * div1, &sn1, &cs1);
  float4 r;
  r.x = e.x + sn0; r.y = e.y + cs0; r.z = e.z + sn1; r.w = e.w + cs1;
  *(float4*)&x[(size_t)row * 1024 + d0] = r;
}

// ---------------- layernorm (f32 in -> bf16 out) ----------------
__global__ __launch_bounds__(256) void ln_kernel(
    const float* __restrict__ x, const float* __restrict__ g,
    const float* __restrict__ b, u16* __restrict__ y)
{
  int row = blockIdx.x, tid = threadIdx.x;
  float4 v = *(const float4*)&x[(size_t)row * 1024 + tid * 4];
  float sum = v.x + v.y + v.z + v.w;
  float sq = v.x * v.x + v.y * v.y + v.z * v.z + v.w * v.w;
#pragma unroll
  for (int o = 32; o > 0; o >>= 1) {
    sum += __shfl_xor(sum, o, 64);
    sq  += __shfl_xor(sq,  o, 64);
  }
  __shared__ float ps[8];
  int w = tid >> 6;
  if ((tid & 63) == 0) { ps[w] = sum; ps[4 + w] = sq; }
  __syncthreads();
  sum = ps[0] + ps[1] + ps[2] + ps[3];
  sq  = ps[4] + ps[5] + ps[6] + ps[7];
  float mu = sum * (1.0f / 1024.0f);
  float var = sq * (1.0f / 1024.0f) - mu * mu;
  float rs = rsqrtf(var + 1e-5f);
  float4 gg = *(const float4*)&g[tid * 4];
  float4 bb = *(const float4*)&b[tid * 4];
  u32 lo = (u32)f2bf((v.x - mu) * rs * gg.x + bb.x) |
           ((u32)f2bf((v.y - mu) * rs * gg.y + bb.y) << 16);
  u32 hi = (u32)f2bf((v.z - mu) * rs * gg.z + bb.z) |
           ((u32)f2bf((v.w - mu) * rs * gg.w + bb.w) << 16);
  uint2 o2; o2.x = lo; o2.y = hi;
  *(uint2*)&y[(size_t)row * 1024 + tid * 4] = o2;
}

// ---------------- GEMM 128x128 (2-barrier structure) for N=1024 shapes ----
// Rows in LDS are 64 elems = 128B = 8 chunks of 16B; XOR-swizzle chunk^=(row&7)
// (pre-swizzled global source, swizzled ds_read) -> 2-way banks (free).
// OMODE 0: bf16 out; 1: f32 out with f32 residual add; 2: f32 out
template<int OMODE, int RELU>
__global__ __launch_bounds__(256) void gemm_bt(
    const u16* __restrict__ A, const u16* __restrict__ Bt,
    const float* __restrict__ bias, const float* res, void* Cp,
    int M, int N, int K)
{
  __shared__ alignas(16) u16 As[128 * 64];
  __shared__ alignas(16) u16 Bs[128 * 64];
  int tid = threadIdx.x;
  int w = tid >> 6, l = tid & 63;
  int g = l >> 4, lr = l & 15;
  int wm = w >> 1, wn = w & 1;
  int m0 = blockIdx.y * 128, n0 = blockIdx.x * 128;
  f32x4 acc[4][4];
#pragma unroll
  for (int i = 0; i < 4; ++i)
#pragma unroll
    for (int j = 0; j < 4; ++j) acc[i][j] = f32x4{0.f, 0.f, 0.f, 0.f};
  int srow = tid >> 3;
  int scol = (((tid & 7) ^ (srow & 7))) * 8;   // inverse-swizzled source chunk
  const u16* Ab = A  + (size_t)(m0 + srow) * K + scol;
  const u16* Bb = Bt + (size_t)(n0 + srow) * K + scol;
  int nk = K >> 6;
  for (int kt = 0; kt < nk; ++kt) {
    int k0 = kt << 6;
#pragma unroll
    for (int i = 0; i < 4; ++i) {
      GLD16(Ab + (size_t)(i * 32) * K + k0, As + i * 2048 + w * 512);
      GLD16(Bb + (size_t)(i * 32) * K + k0, Bs + i * 2048 + w * 512);
    }
    __syncthreads();
    s16x8 af[4][2], bf[4][2];
#pragma unroll
    for (int mt = 0; mt < 4; ++mt)
#pragma unroll
      for (int ks = 0; ks < 2; ++ks)
        af[mt][ks] = *(const s16x8*)&As[(wm * 64 + mt * 16 + lr) * 64 +
                                        (((ks * 4 + g) ^ (lr & 7)) * 8)];
#pragma unroll
    for (int nt = 0; nt < 4; ++nt)
#pragma unroll
      for (int ks = 0; ks < 2; ++ks)
        bf[nt][ks] = *(const s16x8*)&Bs[(wn * 64 + nt * 16 + lr) * 64 +
                                        (((ks * 4 + g) ^ (lr & 7)) * 8)];
#pragma unroll
    for (int ks = 0; ks < 2; ++ks)
#pragma unroll
      for (int mt = 0; mt < 4; ++mt)
#pragma unroll
        for (int nt = 0; nt < 4; ++nt)
          acc[mt][nt] = mfma16(af[mt][ks], bf[nt][ks], acc[mt][nt]);
    __syncthreads();
  }
#pragma unroll
  for (int mt = 0; mt < 4; ++mt) {
    int row = m0 + wm * 64 + mt * 16 + g * 4;
#pragma unroll
    for (int nt = 0; nt < 4; ++nt) {
      int col = n0 + wn * 64 + nt * 16 + lr;
      float bv = bias[col];
#pragma unroll
      for (int r = 0; r < 4; ++r) {
        float v = acc[mt][nt][r] + bv;
        if (RELU) v = fmaxf(v, 0.f);
        size_t idx = (size_t)(row + r) * N + col;
        if (OMODE == 0)      ((u16*)Cp)[idx] = f2bf(v);
        else if (OMODE == 1) ((float*)Cp)[idx] = v + res[idx];
        else                 ((float*)Cp)[idx] = v;
      }
    }
  }
}

// ---------------- GEMM 256x256, BK=32, 8 waves, ring-4 depth-3 pipeline ----
// C[M,N] = A[M,K] @ Bt[N,K] + bias.  OMODE 0: bf16 out; 2: f32 out.
// grid: 1D, nwg = (M/256)*(N/256), nwg % 8 == 0 required.  gy = M/256.
// LDS rows 32 elems = 64B = 4 chunks; swizzle chunk ^= (row>>1)&3.
template<int OMODE, int RELU>
__global__ __launch_bounds__(512, 2) void gemm256(
    const u16* __restrict__ A, const u16* __restrict__ Bt,
    const float* __restrict__ bias, void* Cp, int M, int N, int K, int gy)
{
  // ring-4 buffers: each 32 KB = A[256][32] bf16 (8192 el) | B[256][32]
  __shared__ alignas(16) u16 lds[4][16384];
  const int tid = threadIdx.x;
  const int w = tid >> 6, l = tid & 63;
  const int g = l >> 4, lr = l & 15;
  const int wm = w >> 2, wn = w & 3;            // 2 x 4 waves, wave tile 128x64
  int nwg = gridDim.x;
  int bid = blockIdx.x;
  int swz = (bid & 7) * (nwg >> 3) + (bid >> 3);
  int by = swz % gy, bx = swz / gy;             // by-major: consecutive share B panel
  int m0 = by << 8, n0 = bx << 8;

  // staging: thread stages 2x16B for A and 2x16B for B per K-tile.
  // LDS dest linear (idx*16B); global source chunk inverse-swizzled.
  const u16* Ag[2]; const u16* Bg[2]; int dstE[2];
#pragma unroll
  for (int s2 = 0; s2 < 2; ++s2) {
    int idx = s2 * 512 + tid;
    int row = idx >> 2;
    int ch = (idx & 3) ^ ((row >> 1) & 3);      // involutive chunk swizzle
    Ag[s2] = A  + (size_t)(m0 + row) * K + ch * 8;
    Bg[s2] = Bt + (size_t)(n0 + row) * K + ch * 8;
    dstE[s2] = idx * 8;
  }
  // fragment read offsets (elements): chunk g ^ ((row>>1)&3), row%16 == lr
  const int colx = (g ^ ((lr >> 1) & 3)) * 8;
  const int aoff = (wm * 128 + lr) * 32 + colx;        // + mf*512
  const int boff = 8192 + (wn * 64 + lr) * 32 + colx;  // + nf*512

  f32x4 acc[8][4];
#pragma unroll
  for (int i = 0; i < 8; ++i)
#pragma unroll
    for (int j = 0; j < 4; ++j) acc[i][j] = f32x4{0.f, 0.f, 0.f, 0.f};

  const int nk = K >> 5;
  // prologue: stage tiles 0,1,2
#pragma unroll
  for (int pt = 0; pt < 3; ++pt) {
    u16* buf = &lds[pt][0];
#pragma unroll
    for (int s2 = 0; s2 < 2; ++s2) GLD16(Ag[s2] + pt * 32, buf + dstE[s2]);
#pragma unroll
    for (int s2 = 0; s2 < 2; ++s2) GLD16(Bg[s2] + pt * 32, buf + 8192 + dstE[s2]);
  }
  asm volatile("s_waitcnt vmcnt(8)" ::: "memory");   // tile 0 landed
  __builtin_amdgcn_s_barrier();

  u16* p0 = &lds[0][0];
  u16* p1 = &lds[1][0];
  u16* p2 = &lds[2][0];
  u16* p3 = &lds[3][0];   // staging target (t+3); read finished at tile t-1
  for (int t = 0; t < nk; ++t) {
    const int k3 = t * 32 + 96;
    const bool st = (t + 3 < nk);
    s16x8 af[4], bf4[4];
    // ---- phase 0: A-frags 0..3 + all B-frags; stage A(t+3) ----
#pragma unroll
    for (int i = 0; i < 4; ++i) af[i] = *(const s16x8*)&p0[aoff + i * 512];
#pragma unroll
    for (int j = 0; j < 4; ++j) bf4[j] = *(const s16x8*)&p0[boff + j * 512];
    if (st) {
#pragma unroll
      for (int s2 = 0; s2 < 2; ++s2) GLD16(Ag[s2] + k3, p3 + dstE[s2]);
    }
    __builtin_amdgcn_s_barrier();
    asm volatile("s_waitcnt lgkmcnt(0)" ::: "memory");
    __builtin_amdgcn_sched_barrier(0);
    __builtin_amdgcn_s_setprio(1);
#pragma unroll
    for (int i = 0; i < 4; ++i)
#pragma unroll
      for (int j = 0; j < 4; ++j) acc[i][j] = mfma16(af[i], bf4[j], acc[i][j]);
    __builtin_amdgcn_s_setprio(0);
    __builtin_amdgcn_s_barrier();
    // ---- phase 1: A-frags 4..7 (B reused); stage B(t+3) ----
#pragma unroll
    for (int i = 0; i < 4; ++i) af[i] = *(const s16x8*)&p0[aoff + (4 + i) * 512];
    if (st) {
#pragma unroll
      for (int s2 = 0; s2 < 2; ++s2) GLD16(Bg[s2] + k3, p3 + 8192 + dstE[s2]);
    }
    __builtin_amdgcn_s_barrier();
    asm volatile("s_waitcnt lgkmcnt(0)" ::: "memory");
    __builtin_amdgcn_sched_barrier(0);
    __builtin_amdgcn_s_setprio(1);
#pragma unroll
    for (int i = 0; i < 4; ++i)
#pragma unroll
      for (int j = 0; j < 4; ++j) acc[4 + i][j] = mfma16(af[i], bf4[j], acc[4 + i][j]);
    __builtin_amdgcn_s_setprio(0);
    // counted drain: ensure tile t+1 landed; deeper tiles stay in flight
    int crem = nk - 1 - t;
    if (crem >= 3)      asm volatile("s_waitcnt vmcnt(8)" ::: "memory");
    else if (crem == 2) asm volatile("s_waitcnt vmcnt(4)" ::: "memory");
    else if (crem == 1) asm volatile("s_waitcnt vmcnt(0)" ::: "memory");
    __builtin_amdgcn_s_barrier();
    u16* tmp = p0; p0 = p1; p1 = p2; p2 = p3; p3 = tmp;  // rotate ring
  }
  // ---- epilogue ----
#pragma unroll
  for (int mf = 0; mf < 8; ++mf) {
    int row = m0 + wm * 128 + mf * 16 + g * 4;
#pragma unroll
    for (int nf = 0; nf < 4; ++nf) {
      int col = n0 + wn * 64 + nf * 16 + lr;
      float bv = bias[col];
#pragma unroll
      for (int r = 0; r < 4; ++r) {
        float v = acc[mf][nf][r] + bv;
        if (RELU) v = fmaxf(v, 0.f);
        size_t idx = (size_t)(row + r) * N + col;
        if (OMODE == 0) ((u16*)Cp)[idx] = f2bf(v);
        else            ((float*)Cp)[idx] = v;
      }
    }
  }
}

// ---------------- flash attention ----------------
__global__ __launch_bounds__(256) void attn_kernel(
    const u16* __restrict__ qkv, u16* __restrict__ outp)
{
  int b = blockIdx.x >> 4, h = blockIdx.x & 15;
  int q0 = blockIdx.y << 6;
  int tid = threadIdx.x, w = tid >> 6, l = tid & 63;
  int g = l >> 4, lr = l & 15;
  const int RS = 3072;
  const u16* base = qkv + (size_t)b * 1024 * RS + h * 64;
  const u16* Qb = base;
  const u16* Kb = base + 1024;
  const u16* Vb = base + 2048;
  __shared__ alignas(16) u16 Plds[4][1024];
  __shared__ alignas(16) u16 Vt[4096];
  char* Pw = (char*)&Plds[w][0];

  s16x8 qf[2];
#pragma unroll
  for (int ks = 0; ks < 2; ++ks)
    qf[ks] = *(const s16x8*)&Qb[(size_t)(q0 + w * 16 + lr) * RS + ks * 32 + g * 8];

  f32x4 o[4];
#pragma unroll
  for (int n = 0; n < 4; ++n) o[n] = f32x4{0.f, 0.f, 0.f, 0.f};
  float mr[4] = {-INFINITY, -INFINITY, -INFINITY, -INFINITY};
  float ls[4] = {0.f, 0.f, 0.f, 0.f};

  int ntile = (q0 >> 6) + 1;
  for (int kt = 0; kt < ntile; ++kt) {
    int kv0 = kt << 6;
    f32x4 sc[4];
#pragma unroll
    for (int t = 0; t < 4; ++t) sc[t] = f32x4{0.f, 0.f, 0.f, 0.f};
#pragma unroll
    for (int ks = 0; ks < 2; ++ks)
#pragma unroll
      for (int t = 0; t < 4; ++t) {
        s16x8 kf = *(const s16x8*)&Kb[(size_t)(kv0 + t * 16 + lr) * RS + ks * 32 + g * 8];
        sc[t] = mfma16(qf[ks], kf, sc[t]);
      }
#pragma unroll
    for (int p = 0; p < 2; ++p) {
      int key = p * 32 + (tid >> 3);
      int d0 = (tid & 7) * 8;
      s16x8 vrow = *(const s16x8*)&Vb[(size_t)(kv0 + key) * RS + d0];
#pragma unroll
      for (int j = 0; j < 8; ++j) {
        int d = d0 + j;
        int byt = (d * 128 + key * 2) ^ ((d & 7) << 4);
        *(u16*)((char*)Vt + byt) = (u16)vrow[j];
      }
    }
    float p4[4][4];
    float tmax[4] = {-INFINITY, -INFINITY, -INFINITY, -INFINITY};
    int qr_base = q0 + w * 16 + g * 4;
#pragma unroll
    for (int t = 0; t < 4; ++t) {
      int key = kv0 + t * 16 + lr;
#pragma unroll
      for (int r = 0; r < 4; ++r) {
        float s = sc[t][r] * 0.125f;
        s = (key <= qr_base + r) ? s : -1e30f;
        p4[t][r] = s;
        tmax[r] = fmaxf(tmax[r], s);
      }
    }
#pragma unroll
    for (int off = 1; off < 16; off <<= 1)
#pragma unroll
      for (int r = 0; r < 4; ++r) tmax[r] = fmaxf(tmax[r], __shfl_xor(tmax[r], off, 64));
    float corr[4], rsum[4];
#pragma unroll
    for (int r = 0; r < 4; ++r) {
      float mn = fmaxf(mr[r], tmax[r]);
      corr[r] = __expf(mr[r] - mn);
      mr[r] = mn;
      rsum[r] = 0.f;
    }
#pragma unroll
    for (int t = 0; t < 4; ++t)
#pragma unroll
      for (int r = 0; r < 4; ++r) {
        float e = __expf(p4[t][r] - mr[r]);
        p4[t][r] = e;
        rsum[r] += e;
      }
#pragma unroll
    for (int off = 1; off < 16; off <<= 1)
#pragma unroll
      for (int r = 0; r < 4; ++r) rsum[r] += __shfl_xor(rsum[r], off, 64);
#pragma unroll
    for (int r = 0; r < 4; ++r) ls[r] = ls[r] * corr[r] + rsum[r];
#pragma unroll
    for (int n = 0; n < 4; ++n)
#pragma unroll
      for (int r = 0; r < 4; ++r) o[n][r] *= corr[r];
#pragma unroll
    for (int t = 0; t < 4; ++t)
#pragma unroll
      for (int r = 0; r < 4; ++r) {
        int prow = g * 4 + r;
        int byt = (prow * 128 + (t * 16 + lr) * 2) ^ ((prow & 7) << 4);
        *(u16*)(Pw + byt) = f2bf(p4[t][r]);
      }
    __syncthreads();
#pragma unroll
    for (int ks = 0; ks < 2; ++ks) {
      int ab = (lr * 128 + ks * 64 + g * 16) ^ ((lr & 7) << 4);
      s16x8 pa = *(const s16x8*)(Pw + ab);
#pragma unroll
      for (int n = 0; n < 4; ++n) {
        int vb2 = ((n * 16 + lr) * 128 + ks * 64 + g * 16) ^ ((lr & 7) << 4);
        s16x8 vfr = *(const s16x8*)((const char*)Vt + vb2);
        o[n] = mfma16(pa, vfr, o[n]);
      }
    }
    __syncthreads();
  }
#pragma unroll
  for (int n = 0; n < 4; ++n)
#pragma unroll
    for (int r = 0; r < 4; ++r) {
      float v = o[n][r] / ls[r];
      outp[(size_t)(b * 1024 + q0 + w * 16 + g * 4 + r) * 1024 + h * 64 + n * 16 + lr] = f2bf(v);
    }
}

// ---------------- launch ----------------
extern "C" void kernel_launch(void* const* d_in, const int* in_sizes, int n_in,
                              void* d_out, int out_size, void* d_ws, size_t ws_size,
                              hipStream_t stream)
{
  const int*   tokens = (const int*)  d_in[0];
  const float* embW   = (const float*)d_in[1];
  const float* Wq     = (const float*)d_in[2];
  const float* bq     = (const float*)d_in[3];
  const float* Wk     = (const float*)d_in[4];
  const float* bk     = (const float*)d_in[5];
  const float* Wv     = (const float*)d_in[6];
  const float* bv     = (const float*)d_in[7];
  const float* Wo     = (const float*)d_in[8];
  const float* bo     = (const float*)d_in[9];
  const float* ln1g   = (const float*)d_in[10];
  const float* ln1b   = (const float*)d_in[11];
  const float* ln2g   = (const float*)d_in[12];
  const float* ln2b   = (const float*)d_in[13];
  const float* W1     = (const float*)d_in[14];
  const float* b1     = (const float*)d_in[15];
  const float* W2     = (const float*)d_in[16];
  const float* b2     = (const float*)d_in[17];
  const float* lnfg   = (const float*)d_in[18];
  const float* lnfb   = (const float*)d_in[19];
  const float* headW  = (const float*)d_in[20];
  const float* headb  = (const float*)d_in[21];
  (void)in_sizes; (void)n_in; (void)out_size;

  char* ws = (char*)d_ws;
  u16*   qkvT = (u16*)(ws);               // [8][3072][1024] bf16
  u16*   woT  = (u16*)(ws + 50331648);    // [8][1024][1024]
  u16*   w1T  = (u16*)(ws + 67108864);    // [8][4096][1024]
  u16*   w2T  = (u16*)(ws + 134217728);   // [8][1024][4096]
  u16*   headT= (u16*)(ws + 201326592);   // [32000][1024]
  float* bqkv = (float*)(ws + 266862592); // [8][3072]
  float* x    = (float*)(ws + 266960896); // [4096][1024] f32 residual stream
  u16*   y    = (u16*)(ws + 283738112);   // [4096][1024] bf16 LN output
  u16*   qkv  = (u16*)(ws + 292126720);   // [4096][3072] bf16
  u16*   attno= (u16*)(ws + 317292544);   // [4096][1024] bf16
  u16*   h1   = (u16*)(ws + 325681152);   // [4096][4096] bf16
  if (ws_size < 359235584ull) return;     // need ~360 MB scratch

  dim3 blk(256);
  dim3 blk5(512);
  // weight prep
  transpose_cvt<<<dim3(32, 32, 8),  blk, 0, stream>>>(Wq, qkvT,           1024,  1048576LL, 3145728LL, 1024);
  transpose_cvt<<<dim3(32, 32, 8),  blk, 0, stream>>>(Wk, qkvT + 1048576, 1024,  1048576LL, 3145728LL, 1024);
  transpose_cvt<<<dim3(32, 32, 8),  blk, 0, stream>>>(Wv, qkvT + 2097152, 1024,  1048576LL, 3145728LL, 1024);
  transpose_cvt<<<dim3(32, 32, 8),  blk, 0, stream>>>(Wo, woT,            1024,  1048576LL, 1048576LL, 1024);
  transpose_cvt<<<dim3(32, 128, 8), blk, 0, stream>>>(W1, w1T,            4096,  4194304LL, 4194304LL, 1024);
  transpose_cvt<<<dim3(128, 32, 8), blk, 0, stream>>>(W2, w2T,            1024,  4194304LL, 4194304LL, 4096);
  transpose_cvt<<<dim3(32, 1000, 1),blk, 0, stream>>>(headW, headT,       32000, 0LL,       0LL,       1024);
  pack_bqkv<<<96, blk, 0, stream>>>(bq, bk, bv, bqkv);
  // embedding
  embed_kernel<<<4096, blk, 0, stream>>>(tokens, embW, x);
  // layers
  for (int ly = 0; ly < 8; ++ly) {
    ln_kernel<<<4096, blk, 0, stream>>>(x, ln1g + ly * 1024, ln1b + ly * 1024, y);
    gemm256<0, 0><<<192, blk5, 0, stream>>>(y, qkvT + (size_t)ly * 3145728,
        bqkv + ly * 3072, qkv, 4096, 3072, 1024, 16);
    attn_kernel<<<dim3(64, 16), blk, 0, stream>>>(qkv, attno);
    gemm_bt<1, 0><<<dim3(8, 32), blk, 0, stream>>>(attno, woT + (size_t)ly * 1048576,
        bo + ly * 1024, x, x, 4096, 1024, 1024);
    ln_kernel<<<4096, blk, 0, stream>>>(x, ln2g + ly * 1024, ln2b + ly * 1024, y);
    gemm256<0, 1><<<256, blk5, 0, stream>>>(y, w1T + (size_t)ly * 4194304,
        b1 + ly * 4096, h1, 4096, 4096, 1024, 16);
    gemm_bt<1, 0><<<dim3(8, 32), blk, 0, stream>>>(h1, w2T + (size_t)ly * 4194304,
        b2 + ly * 1024, x, x, 4096, 1024, 4096);
  }
  // final LN + head
  ln_kernel<<<4096, blk, 0, stream>>>(x, lnfg, lnfb, y);
  gemm256<2, 0><<<2000, blk5, 0, stream>>>(y, headT, headb,
      (float*)d_out, 4096, 32000, 1024, 16);
}